// Round 12
// baseline (182.916 us; speedup 1.0000x reference)
//
#include <hip/hip_runtime.h>

#define BB 2
#define SEQ 2048
#define DIM 768
#define NH 12
#define HD 64

typedef _Float16 half8 __attribute__((ext_vector_type(8)));
typedef _Float16 h4v __attribute__((ext_vector_type(4)));
typedef __fp16 f16x2 __attribute__((ext_vector_type(2)));
typedef float floatx4 __attribute__((ext_vector_type(4)));

// Async global->LDS DMA, 16 B per lane; LDS dest = wave-uniform base + lane*16.
__device__ __forceinline__ void gl_lds16(const _Float16* g, _Float16* l) {
    __builtin_amdgcn_global_load_lds(
        (const __attribute__((address_space(1))) void*)g,
        (__attribute__((address_space(3))) void*)l, 16, 0, 0);
}

// pack 4 floats -> 4 halves via 2x v_cvt_pkrtz
__device__ __forceinline__ h4v pack4(float a, float b, float c, float d) {
    union { f16x2 h2[2]; h4v h4; } u;
    u.h2[0] = __builtin_amdgcn_cvt_pkrtz(a, b);
    u.h2[1] = __builtin_amdgcn_cvt_pkrtz(c, d);
    return u.h4;
}

// ---------------------------------------------------------------------------
// One-shot fp32 -> f16 convert for x, W_kqv, W_proj (block ranges).
// ---------------------------------------------------------------------------
__global__ __launch_bounds__(256)
void cvt3(const float* __restrict__ s0, _Float16* __restrict__ d0, int nb0,
          const float* __restrict__ s1, _Float16* __restrict__ d1, int nb1,
          const float* __restrict__ s2, _Float16* __restrict__ d2) {
    int b = blockIdx.x;
    const float* s; _Float16* d;
    if (b < nb0)            { s = s0; d = d0; }
    else if (b < nb0 + nb1) { s = s1; d = d1; b -= nb0; }
    else                    { s = s2; d = d2; b -= nb0 + nb1; }
    const int i = (b * 256 + threadIdx.x) * 8;
    float4 a = *(const float4*)(s + i);
    float4 c = *(const float4*)(s + i + 4);
    half8 h;
    h[0] = (_Float16)a.x; h[1] = (_Float16)a.y; h[2] = (_Float16)a.z; h[3] = (_Float16)a.w;
    h[4] = (_Float16)c.x; h[5] = (_Float16)c.y; h[6] = (_Float16)c.z; h[7] = (_Float16)c.w;
    *(half8*)(d + i) = h;
}

// ---------------------------------------------------------------------------
// Pipelined GEMM core: BM=BN=128, BK=32, 4 waves (2x2), 3 LDS buffers,
// prefetch DISTANCE 2 with counted vmcnt (never drain to 0 mid-loop).
// Caller must define m0, c0 (output tile origin) before expanding.
// LDS = 48 KB (3 blocks/CU).
// ---------------------------------------------------------------------------
#define GEMM_CORE_P(APTR, BPTR)                                                 \
    __shared__ _Float16 Asl[3][128 * 32];                                       \
    __shared__ _Float16 Bsl[3][128 * 32];                                       \
    const int t = threadIdx.x, w = t >> 6, lane = t & 63;                       \
    const int quad = lane >> 4, l15 = lane & 15;                                \
    const int wm = w >> 1, wn = w & 1;                                          \
    const floatx4 z4 = {0.f, 0.f, 0.f, 0.f};                                    \
    floatx4 acc[4][4];                                                          \
    _Pragma("unroll") for (int i = 0; i < 4; ++i)                               \
        _Pragma("unroll") for (int j = 0; j < 4; ++j) acc[i][j] = z4;           \
    const _Float16* pA = APTR + (size_t)(m0 + w * 32 + l15) * DIM + quad * 8;   \
    const _Float16* pB = BPTR + (size_t)(c0 + w * 32 + l15) * DIM + quad * 8;   \
    _Pragma("unroll") for (int pt = 0; pt < 2; ++pt) {                          \
        gl_lds16(pA + pt * 32,            &Asl[pt][(w * 2 + 0) * 512]);         \
        gl_lds16(pA + pt * 32 + 16 * DIM, &Asl[pt][(w * 2 + 1) * 512]);         \
        gl_lds16(pB + pt * 32,            &Bsl[pt][(w * 2 + 0) * 512]);         \
        gl_lds16(pB + pt * 32 + 16 * DIM, &Bsl[pt][(w * 2 + 1) * 512]);         \
    }                                                                           \
    int cur = 0, pre = 2;                                                       \
    for (int it = 0; it < DIM / 32; ++it) {                                     \
        if (it + 1 < DIM / 32)                                                  \
            asm volatile("s_waitcnt vmcnt(4) lgkmcnt(0)" ::: "memory");         \
        else                                                                    \
            asm volatile("s_waitcnt vmcnt(0) lgkmcnt(0)" ::: "memory");         \
        __builtin_amdgcn_s_barrier();                                           \
        __builtin_amdgcn_sched_barrier(0);                                      \
        if (it + 2 < DIM / 32) {                                                \
            const int k2 = (it + 2) * 32;                                       \
            gl_lds16(pA + k2,            &Asl[pre][(w * 2 + 0) * 512]);         \
            gl_lds16(pA + k2 + 16 * DIM, &Asl[pre][(w * 2 + 1) * 512]);         \
            gl_lds16(pB + k2,            &Bsl[pre][(w * 2 + 0) * 512]);         \
            gl_lds16(pB + k2 + 16 * DIM, &Bsl[pre][(w * 2 + 1) * 512]);         \
        }                                                                       \
        half8 af[4], bf[4];                                                     \
        _Pragma("unroll") for (int i = 0; i < 4; ++i)                           \
            af[i] = *(const half8*)&Asl[cur][(wm * 4 + i) * 512 + lane * 8];    \
        _Pragma("unroll") for (int j = 0; j < 4; ++j)                           \
            bf[j] = *(const half8*)&Bsl[cur][(wn * 4 + j) * 512 + lane * 8];    \
        _Pragma("unroll") for (int i = 0; i < 4; ++i)                           \
            _Pragma("unroll") for (int j = 0; j < 4; ++j)                       \
                acc[i][j] = __builtin_amdgcn_mfma_f32_16x16x32_f16(             \
                    af[i], bf[j], acc[i][j], 0, 0, 0);                          \
        cur = (cur == 2) ? 0 : cur + 1;                                         \
        pre = (pre == 2) ? 0 : pre + 1;                                         \
    }

// KQV: 576 blocks, XCD-swizzled (576 = 8*72 -> 4 A-panels/XCD, L2-resident).
__global__ __launch_bounds__(256)
void kqv_gemm2(const _Float16* __restrict__ xh, const _Float16* __restrict__ Wh,
               const float* __restrict__ bias, _Float16* __restrict__ kb,
               _Float16* __restrict__ qb, _Float16* __restrict__ vbT) {
    const int hw = blockIdx.x;
    const int lg = (hw & 7) * 72 + (hw >> 3);      // bijective: 576 = 8*72
    const int m0 = (lg / 18) * 128, c0 = (lg % 18) * 128;
    GEMM_CORE_P(xh, Wh)
    #pragma unroll
    for (int j = 0; j < 4; ++j) {
        const int cbase = c0 + (wn * 4 + j) * 16;
        const int h = cbase / 192;
        const int rem = cbase - h * 192;
        const int part = rem >> 6;
        const float bv = bias[cbase + l15];
        const int d = (rem & 63) + l15;
        if (part == 2) {
            // V: transposed store (block rows within one batch: m0 % 128 == 0)
            const int bidx = m0 >> 11;
            const int nb = (m0 & (SEQ - 1)) + wm * 64 + quad * 4;
            _Float16* vdst = vbT + ((size_t)(bidx * NH + h) * HD + d) * SEQ;
            #pragma unroll
            for (int i = 0; i < 4; ++i)
                *(h4v*)&vdst[nb + i * 16] =
                    pack4(acc[i][j][0] + bv, acc[i][j][1] + bv,
                          acc[i][j][2] + bv, acc[i][j][3] + bv);
        } else {
            _Float16* dst = (part == 0) ? kb : qb;
            #pragma unroll
            for (int i = 0; i < 4; ++i)
                #pragma unroll
                for (int r = 0; r < 4; ++r) {
                    const int m = m0 + (wm * 4 + i) * 16 + quad * 4 + r;
                    const int bidx = m >> 11, n = m & (SEQ - 1);
                    dst[(((size_t)(bidx * NH + h) * SEQ + n) << 6) + d] =
                        (_Float16)(acc[i][j][r] + bv);
                }
        }
    }
}

// Proj: 192 blocks, XCD-swizzled (192 = 8*24).
__global__ __launch_bounds__(256)
void proj_gemm2(const _Float16* __restrict__ A, const _Float16* __restrict__ Wh,
                const float* __restrict__ bias, float* __restrict__ out) {
    const int hw = blockIdx.x;
    const int lg = (hw & 7) * 24 + (hw >> 3);      // bijective: 192 = 8*24
    const int m0 = (lg / 6) * 128, c0 = (lg % 6) * 128;
    GEMM_CORE_P(A, Wh)
    #pragma unroll
    for (int j = 0; j < 4; ++j) {
        const int cbase = c0 + (wn * 4 + j) * 16;
        const float bv = bias[cbase + l15];
        #pragma unroll
        for (int i = 0; i < 4; ++i)
            #pragma unroll
            for (int r = 0; r < 4; ++r) {
                const int m = m0 + (wm * 4 + i) * 16 + quad * 4 + r;
                out[(size_t)m * DIM + cbase + l15] = acc[i][j][r] + bv;
            }
    }
}

// ---------------------------------------------------------------------------
// Flash attention, MFMA, K-SPLIT, 128-ROW Q-TILE (each staged K/V tile now
// serves 128 q-rows: per-head tile stagings 528 -> 272, blocks 1920 -> 960,
// MFMA per barrier 2x).  Per wave: 32 q-rows as two 16-row groups (rg).
// Fully-masked tiles are skipped per-wave (wave-uniform, no barrier inside).
// XCD-swizzled (960 = 8*120).  LDS = 48 KB -> 3 blocks/CU.
// ---------------------------------------------------------------------------
__global__ __launch_bounds__(256)
void attn_mfma(const _Float16* __restrict__ qb, const _Float16* __restrict__ kbuf,
               const _Float16* __restrict__ vbT, _Float16* __restrict__ sa,
               _Float16* __restrict__ Opart, float* __restrict__ lpart) {
    __shared__ _Float16 Kl[2][64 * 64];
    __shared__ _Float16 Vl[2][64 * 64];
    __shared__ _Float16 Pl[4][32 * 64];
    const int hw = blockIdx.x;
    const int lg = (hw & 7) * 120 + (hw >> 3);     // bijective: 960 = 8*120
    const int bh = lg / 40;
    int u = lg % 40;
    // decode (qt2, p, np); qt2 indexes 128-row q-tiles, T = 2*qt2+2 k-tiles
    int qt2, p, np;
    if (u < 4)       { qt2 = u;                              p = 0;      np = 1; }
    else if (u < 12) { int v = u - 4;  qt2 = 4  + (v >> 1);  p = v & 1;  np = 2; }
    else if (u < 24) { int v = u - 12; qt2 = 8  + v / 3;     p = v % 3;  np = 3; }
    else             { int v = u - 24; qt2 = 12 + (v >> 2);  p = v & 3;  np = 4; }
    const int T = 2 * qt2 + 2;
    const int kt0 = p * 8;
    const int ktn = (p == np - 1) ? (T - kt0) : 8;

    const int t = threadIdx.x, w = t >> 6, lane = t & 63, quad = lane >> 4, l15 = lane & 15;
    const size_t base = (size_t)bh * (SEQ * HD);
    const int i0 = qt2 * 128 + w * 32;             // wave's first q row
    _Float16* Pw = Pl[w];
    const _Float16* Kg = kbuf + base;
    const _Float16* Vg = vbT + base;

    const int lr = lane >> 3, gg = lane & 7;
    const int gs = (gg ^ (lr & 7)) * 8;

    half8 aq[2][2];                                // [rg][ks]
    #pragma unroll
    for (int rg = 0; rg < 2; ++rg) {
        const _Float16* qrow = qb + base + (size_t)(i0 + rg * 16 + l15) * HD;
        aq[rg][0] = *(const half8*)(qrow + quad * 8);
        aq[rg][1] = *(const half8*)(qrow + 32 + quad * 8);
    }
    // fold 1/sqrt(HD) * log2(e) into Q: p = exp2(S)
    const _Float16 qs = (_Float16)(0.125f * 1.44269504f);
    #pragma unroll
    for (int rg = 0; rg < 2; ++rg)
        #pragma unroll
        for (int k = 0; k < 8; ++k) { aq[rg][0][k] *= qs; aq[rg][1][k] *= qs; }

    const floatx4 z4 = {0.f, 0.f, 0.f, 0.f};
    floatx4 O[2][4];
    #pragma unroll
    for (int rg = 0; rg < 2; ++rg)
        #pragma unroll
        for (int dt = 0; dt < 4; ++dt) O[rg][dt] = z4;
    float l_one[2] = {0.f, 0.f};

    // prologue: stage first tile into buffer 0
    #pragma unroll
    for (int pp = 0; pp < 2; ++pp) {
        const int c = w * 2 + pp, row = c * 8 + lr;
        gl_lds16(Kg + (size_t)(kt0 * 64 + row) * HD + gs,  &Kl[0][c * 512]);
        gl_lds16(Vg + (size_t)row * SEQ + kt0 * 64 + gs,   &Vl[0][c * 512]);
    }

    const int swz = l15 & 7;               // K/V read granule swizzle
    const int sswz = (l15 & 7) << 1;       // P granule swizzle (even -> b64-pair safe)

    for (int it = 0; it < ktn; ++it) {
        const int kt = kt0 + it;
        const int buf = it & 1;
        const int j0 = kt * 64;
        __syncthreads();   // staging of `buf` drained; prev compute on buf^1 done

        if (it + 1 < ktn) {
            const _Float16* Kn = Kg + (size_t)(j0 + 64) * HD;
            const _Float16* Vn = Vg + (j0 + 64);
            #pragma unroll
            for (int pp = 0; pp < 2; ++pp) {
                const int c = w * 2 + pp, row = c * 8 + lr;
                gl_lds16(Kn + (size_t)row * HD + gs,  &Kl[buf ^ 1][c * 512]);
                gl_lds16(Vn + (size_t)row * SEQ + gs, &Vl[buf ^ 1][c * 512]);
            }
        }

        const bool active = (j0 <= i0 + 31);       // some row of this wave sees this tile
        const bool diag   = (j0 + 63 > i0);        // masking may be needed
        if (active) {
            #pragma unroll
            for (int rg = 0; rg < 2; ++rg) {
                const int srow = (rg * 16 + l15) * 64;
                // S^T = K * Q^T : lane holds (k = nt*16+quad*4+r, q = rg*16+l15)
                floatx4 S[4];
                #pragma unroll
                for (int nt = 0; nt < 4; ++nt) S[nt] = z4;
                __builtin_amdgcn_s_setprio(1);
                #pragma unroll
                for (int ks = 0; ks < 2; ++ks)
                    #pragma unroll
                    for (int nt = 0; nt < 4; ++nt) {
                        half8 bk = *(const half8*)&Kl[buf][(nt * 16 + l15) * 64 +
                                                           (((ks * 4 + quad) ^ swz) << 3)];
                        S[nt] = __builtin_amdgcn_mfma_f32_16x16x32_f16(bk, aq[rg][ks], S[nt], 0, 0, 0);
                    }
                __builtin_amdgcn_s_setprio(0);

                asm volatile("" ::: "memory");   // WAR: prior P reads before new writes
                if (diag) {                      // masked path (zero where k > q)
                    const int iq = i0 + rg * 16 + l15;
                    #pragma unroll
                    for (int nt = 0; nt < 4; ++nt) {
                        float pv[4];
                        #pragma unroll
                        for (int r = 0; r < 4; ++r) {
                            float pvv = exp2f(S[nt][r]);
                            if (j0 + nt * 16 + quad * 4 + r > iq) pvv = 0.f;
                            l_one[rg] += pvv;
                            pv[r] = pvv;
                        }
                        *(h4v*)&Pw[srow + (((nt * 4 + quad) ^ sswz) << 2)] =
                            pack4(pv[0], pv[1], pv[2], pv[3]);
                    }
                } else {                         // interior tile: no masking ops
                    #pragma unroll
                    for (int nt = 0; nt < 4; ++nt) {
                        float pv[4];
                        #pragma unroll
                        for (int r = 0; r < 4; ++r) {
                            float pvv = exp2f(S[nt][r]);
                            l_one[rg] += pvv;
                            pv[r] = pvv;
                        }
                        *(h4v*)&Pw[srow + (((nt * 4 + quad) ^ sswz) << 2)] =
                            pack4(pv[0], pv[1], pv[2], pv[3]);
                    }
                }
                asm volatile("" ::: "memory");   // RAW: P writes before fragment reads

                __builtin_amdgcn_s_setprio(1);
                #pragma unroll
                for (int ks = 0; ks < 2; ++ks) {
                    half8 ap = *(const half8*)&Pw[srow + (((((ks * 4 + quad) << 1)) ^ sswz) << 2)];
                    #pragma unroll
                    for (int dt = 0; dt < 4; ++dt) {
                        half8 bv = *(const half8*)&Vl[buf][(dt * 16 + l15) * 64 +
                                                            (((ks * 4 + quad) ^ swz) << 3)];
                        O[rg][dt] = __builtin_amdgcn_mfma_f32_16x16x32_f16(ap, bv, O[rg][dt], 0, 0, 0);
                    }
                }
                __builtin_amdgcn_s_setprio(0);
            }
        }
    }

    // softmax denominator per rg: lane holds partial for q = rg*16+l15;
    // quads partition k -> reduce across quads only.
    float rs[2];
    #pragma unroll
    for (int rg = 0; rg < 2; ++rg) {
        float v = l_one[rg];
        v += __shfl_xor(v, 16);
        v += __shfl_xor(v, 32);
        rs[rg] = v;
    }

    if (np == 1) {
        const int bidx = bh / NH, h = bh - bidx * NH;
        #pragma unroll
        for (int rg = 0; rg < 2; ++rg) {
            const float inv = 1.0f / rs[rg];
            #pragma unroll
            for (int r = 0; r < 4; ++r) {
                const float invr = __shfl(inv, quad * 4 + r);   // lane m holds row m
                const int i = i0 + rg * 16 + quad * 4 + r;
                #pragma unroll
                for (int dt = 0; dt < 4; ++dt)
                    sa[(size_t)(bidx * SEQ + i) * DIM + h * HD + dt * 16 + l15] =
                        (_Float16)(O[rg][dt][r] * invr);
            }
        }
    } else {
        // write partials: O (f16, 128x64) and l (fp32, 128), slot (bh, qt2, p)
        const size_t slot = ((size_t)(bh * 16 + qt2) * 4 + p);
        _Float16* Od = Opart + slot * 8192;
        float*    ld = lpart + slot * 128;
        #pragma unroll
        for (int rg = 0; rg < 2; ++rg) {
            if (lane < 16) ld[w * 32 + rg * 16 + lane] = rs[rg];
            #pragma unroll
            for (int r = 0; r < 4; ++r) {
                const int row = w * 32 + rg * 16 + quad * 4 + r;
                #pragma unroll
                for (int dt = 0; dt < 4; ++dt)
                    Od[row * 64 + dt * 16 + l15] = (_Float16)O[rg][dt][r];
            }
        }
    }
}

// ---------------------------------------------------------------------------
// Combine K-split partials: sa = (sum_p O_p) / (sum_p l_p) for qt2 >= 4.
// 128-row slots; 256 thr: row = t>>1, 32 d-cols per thread.
// ---------------------------------------------------------------------------
__global__ __launch_bounds__(256)
void attn_combine(const _Float16* __restrict__ Opart, const float* __restrict__ lpart,
                  _Float16* __restrict__ sa) {
    const int qt2 = 4 + blockIdx.x;
    const int bh = blockIdx.y;
    const int np = (2 * qt2 + 2 + 7) >> 3;
    const int t = threadIdx.x;
    const int row = t >> 1, d0 = (t & 1) * 32;
    const size_t slot0 = ((size_t)(bh * 16 + qt2) * 4);

    float lsum = 0.f;
    for (int p = 0; p < np; ++p) lsum += lpart[(slot0 + p) * 128 + row];

    float acc[32];
    #pragma unroll
    for (int k = 0; k < 32; ++k) acc[k] = 0.f;
    for (int p = 0; p < np; ++p) {
        const _Float16* src = Opart + (slot0 + p) * 8192 + row * 64 + d0;
        #pragma unroll
        for (int v = 0; v < 4; ++v) {
            half8 a = *(const half8*)(src + v * 8);
            #pragma unroll
            for (int k = 0; k < 8; ++k) acc[v * 8 + k] += (float)a[k];
        }
    }
    const float inv = 1.0f / lsum;
    const int bidx = bh / NH, h = bh - bidx * NH;
    _Float16* dst = sa + (size_t)(bidx * SEQ + qt2 * 128 + row) * DIM + h * HD + d0;
    #pragma unroll
    for (int v = 0; v < 4; ++v) {
        half8 o;
        #pragma unroll
        for (int k = 0; k < 8; ++k) o[k] = (_Float16)(acc[v * 8 + k] * inv);
        *(half8*)(dst + v * 8) = o;
    }
}

// ---------------------------------------------------------------------------
extern "C" void kernel_launch(void* const* d_in, const int* in_sizes, int n_in,
                              void* d_out, int out_size, void* d_ws, size_t ws_size,
                              hipStream_t stream) {
    (void)in_sizes; (void)n_in; (void)out_size; (void)ws_size;
    const float* x  = (const float*)d_in[0];
    const float* Wk = (const float*)d_in[1];
    const float* bk = (const float*)d_in[2];
    const float* Wp = (const float*)d_in[3];
    const float* bp = (const float*)d_in[4];
    float* out = (float*)d_out;

    _Float16* ws = (_Float16*)d_ws;
    const size_t per = (size_t)BB * NH * SEQ * HD;          // 3,145,728 halves
    const int nx = BB * SEQ * DIM;                          // 3,145,728
    const int nwk = NH * 3 * HD * DIM;                      // 1,769,472
    const int nwp = DIM * DIM;                              //   589,824
    _Float16* kb  = ws;
    _Float16* qb  = ws + per;
    _Float16* vbT = ws + 3 * per;                           // slot 2 unused
    _Float16* sa  = ws + 4 * per;
    _Float16* xh  = ws + 5 * per;
    _Float16* Wkh = xh + nx;
    _Float16* Wph = Wkh + nwk;
    _Float16* Opart = Wph + nwp;                            // 24*16*4*8192 f16
    float*    lpart = (float*)(Opart + (size_t)24 * 16 * 4 * 8192);

    const int nb0 = nx / 2048, nb1 = nwk / 2048, nb2 = nwp / 2048;
    cvt3<<<dim3(nb0 + nb1 + nb2), 256, 0, stream>>>(x, xh, nb0, Wk, Wkh, nb1, Wp, Wph);

    kqv_gemm2  <<<dim3(576), 256, 0, stream>>>(xh, Wkh, bk, kb, qb, vbT);
    attn_mfma  <<<dim3(960), 256, 0, stream>>>(qb, kb, vbT, sa, Opart, lpart);
    attn_combine<<<dim3(12, 24), 256, 0, stream>>>(Opart, lpart, sa);
    proj_gemm2 <<<dim3(192), 256, 0, stream>>>(sa, Wph, bp, out);
}

// Round 13
// 175.351 us; speedup vs baseline: 1.0431x; 1.0431x over previous
//
#include <hip/hip_runtime.h>

#define BB 2
#define SEQ 2048
#define DIM 768
#define NH 12
#define HD 64

typedef _Float16 half8 __attribute__((ext_vector_type(8)));
typedef _Float16 h4v __attribute__((ext_vector_type(4)));
typedef __fp16 f16x2 __attribute__((ext_vector_type(2)));
typedef float floatx4 __attribute__((ext_vector_type(4)));

// Async global->LDS DMA, 16 B per lane; LDS dest = wave-uniform base + lane*16.
__device__ __forceinline__ void gl_lds16(const _Float16* g, _Float16* l) {
    __builtin_amdgcn_global_load_lds(
        (const __attribute__((address_space(1))) void*)g,
        (__attribute__((address_space(3))) void*)l, 16, 0, 0);
}

// pack 4 floats -> 4 halves via 2x v_cvt_pkrtz
__device__ __forceinline__ h4v pack4(float a, float b, float c, float d) {
    union { f16x2 h2[2]; h4v h4; } u;
    u.h2[0] = __builtin_amdgcn_cvt_pkrtz(a, b);
    u.h2[1] = __builtin_amdgcn_cvt_pkrtz(c, d);
    return u.h4;
}

// ---------------------------------------------------------------------------
// One-shot fp32 -> f16 convert for x, W_kqv, W_proj (block ranges).
// ---------------------------------------------------------------------------
__global__ __launch_bounds__(256)
void cvt3(const float* __restrict__ s0, _Float16* __restrict__ d0, int nb0,
          const float* __restrict__ s1, _Float16* __restrict__ d1, int nb1,
          const float* __restrict__ s2, _Float16* __restrict__ d2) {
    int b = blockIdx.x;
    const float* s; _Float16* d;
    if (b < nb0)            { s = s0; d = d0; }
    else if (b < nb0 + nb1) { s = s1; d = d1; b -= nb0; }
    else                    { s = s2; d = d2; b -= nb0 + nb1; }
    const int i = (b * 256 + threadIdx.x) * 8;
    float4 a = *(const float4*)(s + i);
    float4 c = *(const float4*)(s + i + 4);
    half8 h;
    h[0] = (_Float16)a.x; h[1] = (_Float16)a.y; h[2] = (_Float16)a.z; h[3] = (_Float16)a.w;
    h[4] = (_Float16)c.x; h[5] = (_Float16)c.y; h[6] = (_Float16)c.z; h[7] = (_Float16)c.w;
    *(half8*)(d + i) = h;
}

// ---------------------------------------------------------------------------
// Pipelined GEMM core: BM=BN=128, BK=32, 4 waves (2x2), 3 LDS buffers,
// prefetch DISTANCE 2 with counted vmcnt (never drain to 0 mid-loop).
// Caller must define m0, c0 (output tile origin) before expanding.
// LDS = 48 KB (3 blocks/CU).
// ---------------------------------------------------------------------------
#define GEMM_CORE_P(APTR, BPTR)                                                 \
    __shared__ _Float16 Asl[3][128 * 32];                                       \
    __shared__ _Float16 Bsl[3][128 * 32];                                       \
    const int t = threadIdx.x, w = t >> 6, lane = t & 63;                       \
    const int quad = lane >> 4, l15 = lane & 15;                                \
    const int wm = w >> 1, wn = w & 1;                                          \
    const floatx4 z4 = {0.f, 0.f, 0.f, 0.f};                                    \
    floatx4 acc[4][4];                                                          \
    _Pragma("unroll") for (int i = 0; i < 4; ++i)                               \
        _Pragma("unroll") for (int j = 0; j < 4; ++j) acc[i][j] = z4;           \
    const _Float16* pA = APTR + (size_t)(m0 + w * 32 + l15) * DIM + quad * 8;   \
    const _Float16* pB = BPTR + (size_t)(c0 + w * 32 + l15) * DIM + quad * 8;   \
    _Pragma("unroll") for (int pt = 0; pt < 2; ++pt) {                          \
        gl_lds16(pA + pt * 32,            &Asl[pt][(w * 2 + 0) * 512]);         \
        gl_lds16(pA + pt * 32 + 16 * DIM, &Asl[pt][(w * 2 + 1) * 512]);         \
        gl_lds16(pB + pt * 32,            &Bsl[pt][(w * 2 + 0) * 512]);         \
        gl_lds16(pB + pt * 32 + 16 * DIM, &Bsl[pt][(w * 2 + 1) * 512]);         \
    }                                                                           \
    int cur = 0, pre = 2;                                                       \
    for (int it = 0; it < DIM / 32; ++it) {                                     \
        if (it + 1 < DIM / 32)                                                  \
            asm volatile("s_waitcnt vmcnt(4) lgkmcnt(0)" ::: "memory");         \
        else                                                                    \
            asm volatile("s_waitcnt vmcnt(0) lgkmcnt(0)" ::: "memory");         \
        __builtin_amdgcn_s_barrier();                                           \
        __builtin_amdgcn_sched_barrier(0);                                      \
        if (it + 2 < DIM / 32) {                                                \
            const int k2 = (it + 2) * 32;                                       \
            gl_lds16(pA + k2,            &Asl[pre][(w * 2 + 0) * 512]);         \
            gl_lds16(pA + k2 + 16 * DIM, &Asl[pre][(w * 2 + 1) * 512]);         \
            gl_lds16(pB + k2,            &Bsl[pre][(w * 2 + 0) * 512]);         \
            gl_lds16(pB + k2 + 16 * DIM, &Bsl[pre][(w * 2 + 1) * 512]);         \
        }                                                                       \
        half8 af[4], bf[4];                                                     \
        _Pragma("unroll") for (int i = 0; i < 4; ++i)                           \
            af[i] = *(const half8*)&Asl[cur][(wm * 4 + i) * 512 + lane * 8];    \
        _Pragma("unroll") for (int j = 0; j < 4; ++j)                           \
            bf[j] = *(const half8*)&Bsl[cur][(wn * 4 + j) * 512 + lane * 8];    \
        _Pragma("unroll") for (int i = 0; i < 4; ++i)                           \
            _Pragma("unroll") for (int j = 0; j < 4; ++j)                       \
                acc[i][j] = __builtin_amdgcn_mfma_f32_16x16x32_f16(             \
                    af[i], bf[j], acc[i][j], 0, 0, 0);                          \
        cur = (cur == 2) ? 0 : cur + 1;                                         \
        pre = (pre == 2) ? 0 : pre + 1;                                         \
    }

// KQV: 576 blocks, XCD-swizzled (576 = 8*72 -> 4 A-panels/XCD, L2-resident).
__global__ __launch_bounds__(256)
void kqv_gemm2(const _Float16* __restrict__ xh, const _Float16* __restrict__ Wh,
               const float* __restrict__ bias, _Float16* __restrict__ kb,
               _Float16* __restrict__ qb, _Float16* __restrict__ vbT) {
    const int hw = blockIdx.x;
    const int lg = (hw & 7) * 72 + (hw >> 3);      // bijective: 576 = 8*72
    const int m0 = (lg / 18) * 128, c0 = (lg % 18) * 128;
    GEMM_CORE_P(xh, Wh)
    #pragma unroll
    for (int j = 0; j < 4; ++j) {
        const int cbase = c0 + (wn * 4 + j) * 16;
        const int h = cbase / 192;
        const int rem = cbase - h * 192;
        const int part = rem >> 6;
        const float bv = bias[cbase + l15];
        const int d = (rem & 63) + l15;
        if (part == 2) {
            // V: transposed store (block rows within one batch: m0 % 128 == 0)
            const int bidx = m0 >> 11;
            const int nb = (m0 & (SEQ - 1)) + wm * 64 + quad * 4;
            _Float16* vdst = vbT + ((size_t)(bidx * NH + h) * HD + d) * SEQ;
            #pragma unroll
            for (int i = 0; i < 4; ++i)
                *(h4v*)&vdst[nb + i * 16] =
                    pack4(acc[i][j][0] + bv, acc[i][j][1] + bv,
                          acc[i][j][2] + bv, acc[i][j][3] + bv);
        } else {
            _Float16* dst = (part == 0) ? kb : qb;
            #pragma unroll
            for (int i = 0; i < 4; ++i)
                #pragma unroll
                for (int r = 0; r < 4; ++r) {
                    const int m = m0 + (wm * 4 + i) * 16 + quad * 4 + r;
                    const int bidx = m >> 11, n = m & (SEQ - 1);
                    dst[(((size_t)(bidx * NH + h) * SEQ + n) << 6) + d] =
                        (_Float16)(acc[i][j][r] + bv);
                }
        }
    }
}

// Proj: 192 blocks, XCD-swizzled (192 = 8*24).
__global__ __launch_bounds__(256)
void proj_gemm2(const _Float16* __restrict__ A, const _Float16* __restrict__ Wh,
                const float* __restrict__ bias, float* __restrict__ out) {
    const int hw = blockIdx.x;
    const int lg = (hw & 7) * 24 + (hw >> 3);      // bijective: 192 = 8*24
    const int m0 = (lg / 6) * 128, c0 = (lg % 6) * 128;
    GEMM_CORE_P(A, Wh)
    #pragma unroll
    for (int j = 0; j < 4; ++j) {
        const int cbase = c0 + (wn * 4 + j) * 16;
        const float bv = bias[cbase + l15];
        #pragma unroll
        for (int i = 0; i < 4; ++i)
            #pragma unroll
            for (int r = 0; r < 4; ++r) {
                const int m = m0 + (wm * 4 + i) * 16 + quad * 4 + r;
                out[(size_t)m * DIM + cbase + l15] = acc[i][j][r] + bv;
            }
    }
}

// ---------------------------------------------------------------------------
// Flash attention, MFMA, K-SPLIT, 128-row q-tile via 8 WAVES (512 threads):
// wave w owns 16 q-rows (i0 = qt2*128 + w*16); all waves share the staged
// K/V tile (2x reuse per staged byte vs 64-row blocks) with NO serial
// doubling of any wave's critical path (R12's mistake).  LDS = 48 KB
// (Kl 16 + Vl 16 + P 8x2) -> 3 blocks/CU x 8 waves = 24 waves/CU.
// Inactive waves (early rows, late tiles) skip compute wave-uniformly.
// XCD-swizzled (960 = 8*120).
// ---------------------------------------------------------------------------
__global__ __launch_bounds__(512, 6)
void attn_mfma(const _Float16* __restrict__ qb, const _Float16* __restrict__ kbuf,
               const _Float16* __restrict__ vbT, _Float16* __restrict__ sa,
               _Float16* __restrict__ Opart, float* __restrict__ lpart) {
    __shared__ _Float16 Kl[2][64 * 64];
    __shared__ _Float16 Vl[2][64 * 64];
    __shared__ _Float16 Pl[8][16 * 64];
    const int hw = blockIdx.x;
    const int lg = (hw & 7) * 120 + (hw >> 3);     // bijective: 960 = 8*120
    const int bh = lg / 40;
    int u = lg % 40;
    // decode (qt2, p, np); qt2 indexes 128-row q-tiles, T = 2*qt2+2 k-tiles
    int qt2, p, np;
    if (u < 4)       { qt2 = u;                              p = 0;      np = 1; }
    else if (u < 12) { int v = u - 4;  qt2 = 4  + (v >> 1);  p = v & 1;  np = 2; }
    else if (u < 24) { int v = u - 12; qt2 = 8  + v / 3;     p = v % 3;  np = 3; }
    else             { int v = u - 24; qt2 = 12 + (v >> 2);  p = v & 3;  np = 4; }
    const int T = 2 * qt2 + 2;
    const int kt0 = p * 8;
    const int ktn = (p == np - 1) ? (T - kt0) : 8;

    const int t = threadIdx.x, w = t >> 6, lane = t & 63, quad = lane >> 4, l15 = lane & 15;
    const size_t base = (size_t)bh * (SEQ * HD);
    const int i0 = qt2 * 128 + w * 16;             // wave's 16 q-rows
    _Float16* Pw = Pl[w];
    const _Float16* Kg = kbuf + base;
    const _Float16* Vg = vbT + base;

    const int lr = lane >> 3, gg = lane & 7;
    const int gs = (gg ^ (lr & 7)) * 8;

    half8 aq[2];
    aq[0] = *(const half8*)(qb + base + (size_t)(i0 + l15) * HD + quad * 8);
    aq[1] = *(const half8*)(qb + base + (size_t)(i0 + l15) * HD + 32 + quad * 8);
    // fold 1/sqrt(HD) * log2(e) into Q: p = exp2(S)
    const _Float16 qs = (_Float16)(0.125f * 1.44269504f);
    #pragma unroll
    for (int k = 0; k < 8; ++k) { aq[0][k] *= qs; aq[1][k] *= qs; }

    const floatx4 z4 = {0.f, 0.f, 0.f, 0.f};
    floatx4 O[4];
    #pragma unroll
    for (int dt = 0; dt < 4; ++dt) O[dt] = z4;
    float l_one = 0.f;

    // prologue: stage first tile into buffer 0 (each wave: 1 K row-group + 1 V)
    {
        const int row = w * 8 + lr;
        gl_lds16(Kg + (size_t)(kt0 * 64 + row) * HD + gs,  &Kl[0][w * 512]);
        gl_lds16(Vg + (size_t)row * SEQ + kt0 * 64 + gs,   &Vl[0][w * 512]);
    }

    const int swz = l15 & 7;               // K/V read granule swizzle
    const int sswz = (l15 & 7) << 1;       // P granule swizzle (even -> b128-safe)
    const int srow = l15 * 64;             // P row base (this lane's q row)

    for (int it = 0; it < ktn; ++it) {
        const int kt = kt0 + it;
        const int buf = it & 1;
        const int j0 = kt * 64;
        __syncthreads();   // staging of `buf` drained; prev compute on buf^1 done

        if (it + 1 < ktn) {
            const _Float16* Kn = Kg + (size_t)(j0 + 64) * HD;
            const _Float16* Vn = Vg + (j0 + 64);
            const int row = w * 8 + lr;
            gl_lds16(Kn + (size_t)row * HD + gs,  &Kl[buf ^ 1][w * 512]);
            gl_lds16(Vn + (size_t)row * SEQ + gs, &Vl[buf ^ 1][w * 512]);
        }

        const bool active = (j0 <= i0 + 15);       // wave sees this tile
        if (!active) continue;                     // wave-uniform; barrier is above
        const bool diag = (j0 + 63 > i0);          // masking may be needed

        // S^T = K * Q^T : lane holds (k = nt*16 + quad*4 + r, q = l15)
        floatx4 S[4];
        #pragma unroll
        for (int nt = 0; nt < 4; ++nt) S[nt] = z4;
        __builtin_amdgcn_s_setprio(1);
        #pragma unroll
        for (int ks = 0; ks < 2; ++ks)
            #pragma unroll
            for (int nt = 0; nt < 4; ++nt) {
                half8 bk = *(const half8*)&Kl[buf][(nt * 16 + l15) * 64 +
                                                   (((ks * 4 + quad) ^ swz) << 3)];
                S[nt] = __builtin_amdgcn_mfma_f32_16x16x32_f16(bk, aq[ks], S[nt], 0, 0, 0);
            }
        __builtin_amdgcn_s_setprio(0);

        asm volatile("" ::: "memory");   // WAR: prior P-frag reads before new writes
        if (diag) {                      // masked path (zero where k > q)
            const int iq = i0 + l15;
            #pragma unroll
            for (int nt = 0; nt < 4; ++nt) {
                float pv[4];
                #pragma unroll
                for (int r = 0; r < 4; ++r) {
                    float pvv = exp2f(S[nt][r]);
                    if (j0 + nt * 16 + quad * 4 + r > iq) pvv = 0.f;
                    l_one += pvv;
                    pv[r] = pvv;
                }
                *(h4v*)&Pw[srow + (((nt * 4 + quad) ^ sswz) << 2)] =
                    pack4(pv[0], pv[1], pv[2], pv[3]);
            }
        } else {                         // interior tile: no masking ops
            #pragma unroll
            for (int nt = 0; nt < 4; ++nt) {
                float pv[4];
                #pragma unroll
                for (int r = 0; r < 4; ++r) {
                    float pvv = exp2f(S[nt][r]);
                    l_one += pvv;
                    pv[r] = pvv;
                }
                *(h4v*)&Pw[srow + (((nt * 4 + quad) ^ sswz) << 2)] =
                    pack4(pv[0], pv[1], pv[2], pv[3]);
            }
        }
        asm volatile("" ::: "memory");   // RAW: P writes before fragment reads

        __builtin_amdgcn_s_setprio(1);
        #pragma unroll
        for (int ks = 0; ks < 2; ++ks) {
            half8 ap = *(const half8*)&Pw[srow + (((((ks * 4 + quad) << 1)) ^ sswz) << 2)];
            #pragma unroll
            for (int dt = 0; dt < 4; ++dt) {
                half8 bv = *(const half8*)&Vl[buf][(dt * 16 + l15) * 64 +
                                                    (((ks * 4 + quad) ^ swz) << 3)];
                O[dt] = __builtin_amdgcn_mfma_f32_16x16x32_f16(ap, bv, O[dt], 0, 0, 0);
            }
        }
        __builtin_amdgcn_s_setprio(0);
    }

    // softmax denominator: lane holds partial for q = l15 over its k subset;
    // quads partition k -> reduce across quads only.
    float rs = l_one;
    rs += __shfl_xor(rs, 16);
    rs += __shfl_xor(rs, 32);

    if (np == 1) {
        const float inv = 1.0f / rs;     // inverse for q-row = l15
        const int bidx = bh / NH, h = bh - bidx * NH;
        #pragma unroll
        for (int r = 0; r < 4; ++r) {
            const float invr = __shfl(inv, quad * 4 + r);   // lane m holds row m
            const int i = i0 + quad * 4 + r;
            #pragma unroll
            for (int dt = 0; dt < 4; ++dt)
                sa[(size_t)(bidx * SEQ + i) * DIM + h * HD + dt * 16 + l15] =
                    (_Float16)(O[dt][r] * invr);
        }
    } else {
        // write partials: O (f16, 128x64) and l (fp32, 128), slot (bh, qt2, p)
        const size_t slot = ((size_t)(bh * 16 + qt2) * 4 + p);
        _Float16* Od = Opart + slot * 8192;
        float*    ld = lpart + slot * 128;
        if (lane < 16) ld[w * 16 + lane] = rs;
        #pragma unroll
        for (int r = 0; r < 4; ++r) {
            const int row = w * 16 + quad * 4 + r;
            #pragma unroll
            for (int dt = 0; dt < 4; ++dt)
                Od[row * 64 + dt * 16 + l15] = (_Float16)O[dt][r];
        }
    }
}

// ---------------------------------------------------------------------------
// Combine K-split partials: sa = (sum_p O_p) / (sum_p l_p) for qt2 >= 4.
// 128-row slots; 256 thr: row = t>>1, 32 d-cols per thread.
// ---------------------------------------------------------------------------
__global__ __launch_bounds__(256)
void attn_combine(const _Float16* __restrict__ Opart, const float* __restrict__ lpart,
                  _Float16* __restrict__ sa) {
    const int qt2 = 4 + blockIdx.x;
    const int bh = blockIdx.y;
    const int np = (2 * qt2 + 2 + 7) >> 3;
    const int t = threadIdx.x;
    const int row = t >> 1, d0 = (t & 1) * 32;
    const size_t slot0 = ((size_t)(bh * 16 + qt2) * 4);

    float lsum = 0.f;
    for (int p = 0; p < np; ++p) lsum += lpart[(slot0 + p) * 128 + row];

    float acc[32];
    #pragma unroll
    for (int k = 0; k < 32; ++k) acc[k] = 0.f;
    for (int p = 0; p < np; ++p) {
        const _Float16* src = Opart + (slot0 + p) * 8192 + row * 64 + d0;
        #pragma unroll
        for (int v = 0; v < 4; ++v) {
            half8 a = *(const half8*)(src + v * 8);
            #pragma unroll
            for (int k = 0; k < 8; ++k) acc[v * 8 + k] += (float)a[k];
        }
    }
    const float inv = 1.0f / lsum;
    const int bidx = bh / NH, h = bh - bidx * NH;
    _Float16* dst = sa + (size_t)(bidx * SEQ + qt2 * 128 + row) * DIM + h * HD + d0;
    #pragma unroll
    for (int v = 0; v < 4; ++v) {
        half8 o;
        #pragma unroll
        for (int k = 0; k < 8; ++k) o[k] = (_Float16)(acc[v * 8 + k] * inv);
        *(half8*)(dst + v * 8) = o;
    }
}

// ---------------------------------------------------------------------------
extern "C" void kernel_launch(void* const* d_in, const int* in_sizes, int n_in,
                              void* d_out, int out_size, void* d_ws, size_t ws_size,
                              hipStream_t stream) {
    (void)in_sizes; (void)n_in; (void)out_size; (void)ws_size;
    const float* x  = (const float*)d_in[0];
    const float* Wk = (const float*)d_in[1];
    const float* bk = (const float*)d_in[2];
    const float* Wp = (const float*)d_in[3];
    const float* bp = (const float*)d_in[4];
    float* out = (float*)d_out;

    _Float16* ws = (_Float16*)d_ws;
    const size_t per = (size_t)BB * NH * SEQ * HD;          // 3,145,728 halves
    const int nx = BB * SEQ * DIM;                          // 3,145,728
    const int nwk = NH * 3 * HD * DIM;                      // 1,769,472
    const int nwp = DIM * DIM;                              //   589,824
    _Float16* kb  = ws;
    _Float16* qb  = ws + per;
    _Float16* vbT = ws + 3 * per;                           // slot 2 unused
    _Float16* sa  = ws + 4 * per;
    _Float16* xh  = ws + 5 * per;
    _Float16* Wkh = xh + nx;
    _Float16* Wph = Wkh + nwk;
    _Float16* Opart = Wph + nwp;                            // 24*16*4*8192 f16
    float*    lpart = (float*)(Opart + (size_t)24 * 16 * 4 * 8192);

    const int nb0 = nx / 2048, nb1 = nwk / 2048, nb2 = nwp / 2048;
    cvt3<<<dim3(nb0 + nb1 + nb2), 256, 0, stream>>>(x, xh, nb0, Wk, Wkh, nb1, Wp, Wph);

    kqv_gemm2  <<<dim3(576), 256, 0, stream>>>(xh, Wkh, bk, kb, qb, vbT);
    attn_mfma  <<<dim3(960), 512, 0, stream>>>(qb, kb, vbT, sa, Opart, lpart);
    attn_combine<<<dim3(12, 24), 256, 0, stream>>>(Opart, lpart, sa);
    proj_gemm2 <<<dim3(192), 256, 0, stream>>>(sa, Wph, bp, out);
}

// Round 14
// 172.565 us; speedup vs baseline: 1.0600x; 1.0161x over previous
//
#include <hip/hip_runtime.h>

#define BB 2
#define SEQ 2048
#define DIM 768
#define NH 12
#define HD 64

typedef _Float16 half8 __attribute__((ext_vector_type(8)));
typedef _Float16 h4v __attribute__((ext_vector_type(4)));
typedef __fp16 f16x2 __attribute__((ext_vector_type(2)));
typedef float floatx4 __attribute__((ext_vector_type(4)));

// Async global->LDS DMA, 16 B per lane; LDS dest = wave-uniform base + lane*16.
__device__ __forceinline__ void gl_lds16(const _Float16* g, _Float16* l) {
    __builtin_amdgcn_global_load_lds(
        (const __attribute__((address_space(1))) void*)g,
        (__attribute__((address_space(3))) void*)l, 16, 0, 0);
}

// pack 4 floats -> 4 halves via 2x v_cvt_pkrtz
__device__ __forceinline__ h4v pack4(float a, float b, float c, float d) {
    union { f16x2 h2[2]; h4v h4; } u;
    u.h2[0] = __builtin_amdgcn_cvt_pkrtz(a, b);
    u.h2[1] = __builtin_amdgcn_cvt_pkrtz(c, d);
    return u.h4;
}

// ---------------------------------------------------------------------------
// One-shot fp32 -> f16 convert for x, W_kqv, W_proj (block ranges).
// ---------------------------------------------------------------------------
__global__ __launch_bounds__(256)
void cvt3(const float* __restrict__ s0, _Float16* __restrict__ d0, int nb0,
          const float* __restrict__ s1, _Float16* __restrict__ d1, int nb1,
          const float* __restrict__ s2, _Float16* __restrict__ d2) {
    int b = blockIdx.x;
    const float* s; _Float16* d;
    if (b < nb0)            { s = s0; d = d0; }
    else if (b < nb0 + nb1) { s = s1; d = d1; b -= nb0; }
    else                    { s = s2; d = d2; b -= nb0 + nb1; }
    const int i = (b * 256 + threadIdx.x) * 8;
    float4 a = *(const float4*)(s + i);
    float4 c = *(const float4*)(s + i + 4);
    half8 h;
    h[0] = (_Float16)a.x; h[1] = (_Float16)a.y; h[2] = (_Float16)a.z; h[3] = (_Float16)a.w;
    h[4] = (_Float16)c.x; h[5] = (_Float16)c.y; h[6] = (_Float16)c.z; h[7] = (_Float16)c.w;
    *(half8*)(d + i) = h;
}

// ---------------------------------------------------------------------------
// Pipelined GEMM core, 8-WAVE (512 thr): BM=BN=128, BK=32, wave-tile 32x64
// (wm = w>>1 in [0,4), wn = w&1), 3 LDS buffers, prefetch distance 2 with
// counted vmcnt (2 loads/wave/tile -> vmcnt(2) mid-loop, never 0).
// 2x waves/SIMD vs the 4-wave core at identical MFMA:load ratio -- attacks
// the stall-dominated profile (MfmaUtil 12%, VALUBusy 11%, both idle).
// LDS = 48 KB -> 3 blocks/CU = 24 waves/CU capacity.
// Caller must define m0, c0 before expanding.
// ---------------------------------------------------------------------------
#define GEMM_CORE_P8(APTR, BPTR)                                                \
    __shared__ _Float16 Asl[3][128 * 32];                                       \
    __shared__ _Float16 Bsl[3][128 * 32];                                       \
    const int t = threadIdx.x, w = t >> 6, lane = t & 63;                       \
    const int quad = lane >> 4, l15 = lane & 15;                                \
    const int wm = w >> 1, wn = w & 1;                                          \
    const floatx4 z4 = {0.f, 0.f, 0.f, 0.f};                                    \
    floatx4 acc[2][4];                                                          \
    _Pragma("unroll") for (int i = 0; i < 2; ++i)                               \
        _Pragma("unroll") for (int j = 0; j < 4; ++j) acc[i][j] = z4;           \
    const _Float16* pA = APTR + (size_t)(m0 + w * 16 + l15) * DIM + quad * 8;   \
    const _Float16* pB = BPTR + (size_t)(c0 + w * 16 + l15) * DIM + quad * 8;   \
    _Pragma("unroll") for (int pt = 0; pt < 2; ++pt) {                          \
        gl_lds16(pA + pt * 32, &Asl[pt][w * 512]);                              \
        gl_lds16(pB + pt * 32, &Bsl[pt][w * 512]);                              \
    }                                                                           \
    int cur = 0, pre = 2;                                                       \
    for (int it = 0; it < DIM / 32; ++it) {                                     \
        if (it + 1 < DIM / 32)                                                  \
            asm volatile("s_waitcnt vmcnt(2) lgkmcnt(0)" ::: "memory");         \
        else                                                                    \
            asm volatile("s_waitcnt vmcnt(0) lgkmcnt(0)" ::: "memory");         \
        __builtin_amdgcn_s_barrier();                                           \
        __builtin_amdgcn_sched_barrier(0);                                      \
        if (it + 2 < DIM / 32) {                                                \
            const int k2 = (it + 2) * 32;                                       \
            gl_lds16(pA + k2, &Asl[pre][w * 512]);                              \
            gl_lds16(pB + k2, &Bsl[pre][w * 512]);                              \
        }                                                                       \
        half8 af[2], bf[4];                                                     \
        _Pragma("unroll") for (int i = 0; i < 2; ++i)                           \
            af[i] = *(const half8*)&Asl[cur][(wm * 2 + i) * 512 + lane * 8];    \
        _Pragma("unroll") for (int j = 0; j < 4; ++j)                           \
            bf[j] = *(const half8*)&Bsl[cur][(wn * 4 + j) * 512 + lane * 8];    \
        _Pragma("unroll") for (int i = 0; i < 2; ++i)                           \
            _Pragma("unroll") for (int j = 0; j < 4; ++j)                       \
                acc[i][j] = __builtin_amdgcn_mfma_f32_16x16x32_f16(             \
                    af[i], bf[j], acc[i][j], 0, 0, 0);                          \
        cur = (cur == 2) ? 0 : cur + 1;                                         \
        pre = (pre == 2) ? 0 : pre + 1;                                         \
    }

// KQV: 576 blocks x 512 thr, XCD-swizzled (576 = 8*72 -> 4 A-panels/XCD).
__global__ __launch_bounds__(512, 6)
void kqv_gemm2(const _Float16* __restrict__ xh, const _Float16* __restrict__ Wh,
               const float* __restrict__ bias, _Float16* __restrict__ kb,
               _Float16* __restrict__ qb, _Float16* __restrict__ vbT) {
    const int hw = blockIdx.x;
    const int lg = (hw & 7) * 72 + (hw >> 3);      // bijective: 576 = 8*72
    const int m0 = (lg / 18) * 128, c0 = (lg % 18) * 128;
    GEMM_CORE_P8(xh, Wh)
    #pragma unroll
    for (int j = 0; j < 4; ++j) {
        const int cbase = c0 + wn * 64 + j * 16;
        const int h = cbase / 192;
        const int rem = cbase - h * 192;
        const int part = rem >> 6;
        const float bv = bias[cbase + l15];
        const int d = (rem & 63) + l15;
        if (part == 2) {
            // V: transposed store (block rows within one batch: m0 % 128 == 0)
            const int bidx = m0 >> 11;
            const int nb = (m0 & (SEQ - 1)) + wm * 32 + quad * 4;
            _Float16* vdst = vbT + ((size_t)(bidx * NH + h) * HD + d) * SEQ;
            #pragma unroll
            for (int i = 0; i < 2; ++i)
                *(h4v*)&vdst[nb + i * 16] =
                    pack4(acc[i][j][0] + bv, acc[i][j][1] + bv,
                          acc[i][j][2] + bv, acc[i][j][3] + bv);
        } else {
            _Float16* dst = (part == 0) ? kb : qb;
            #pragma unroll
            for (int i = 0; i < 2; ++i)
                #pragma unroll
                for (int r = 0; r < 4; ++r) {
                    const int m = m0 + wm * 32 + i * 16 + quad * 4 + r;
                    const int bidx = m >> 11, n = m & (SEQ - 1);
                    dst[(((size_t)(bidx * NH + h) * SEQ + n) << 6) + d] =
                        (_Float16)(acc[i][j][r] + bv);
                }
        }
    }
}

// Proj: 192 blocks x 512 thr, XCD-swizzled (192 = 8*24).
__global__ __launch_bounds__(512, 6)
void proj_gemm2(const _Float16* __restrict__ A, const _Float16* __restrict__ Wh,
                const float* __restrict__ bias, float* __restrict__ out) {
    const int hw = blockIdx.x;
    const int lg = (hw & 7) * 24 + (hw >> 3);      // bijective: 192 = 8*24
    const int m0 = (lg / 6) * 128, c0 = (lg % 6) * 128;
    GEMM_CORE_P8(A, Wh)
    #pragma unroll
    for (int j = 0; j < 4; ++j) {
        const int cbase = c0 + wn * 64 + j * 16;
        const float bv = bias[cbase + l15];
        #pragma unroll
        for (int i = 0; i < 2; ++i)
            #pragma unroll
            for (int r = 0; r < 4; ++r) {
                const int m = m0 + wm * 32 + i * 16 + quad * 4 + r;
                out[(size_t)m * DIM + cbase + l15] = acc[i][j][r] + bv;
            }
    }
}

// ---------------------------------------------------------------------------
// Flash attention, MFMA, K-SPLIT, 128-row q-tile via 8 WAVES (512 threads):
// wave w owns 16 q-rows (i0 = qt2*128 + w*16); all waves share the staged
// K/V tile.  LDS = 48 KB (Kl 16 + Vl 16 + P 8x2) -> 3 blocks/CU.
// Inactive waves (early rows, late tiles) skip compute wave-uniformly.
// XCD-swizzled (960 = 8*120).
// ---------------------------------------------------------------------------
__global__ __launch_bounds__(512, 6)
void attn_mfma(const _Float16* __restrict__ qb, const _Float16* __restrict__ kbuf,
               const _Float16* __restrict__ vbT, _Float16* __restrict__ sa,
               _Float16* __restrict__ Opart, float* __restrict__ lpart) {
    __shared__ _Float16 Kl[2][64 * 64];
    __shared__ _Float16 Vl[2][64 * 64];
    __shared__ _Float16 Pl[8][16 * 64];
    const int hw = blockIdx.x;
    const int lg = (hw & 7) * 120 + (hw >> 3);     // bijective: 960 = 8*120
    const int bh = lg / 40;
    int u = lg % 40;
    // decode (qt2, p, np); qt2 indexes 128-row q-tiles, T = 2*qt2+2 k-tiles
    int qt2, p, np;
    if (u < 4)       { qt2 = u;                              p = 0;      np = 1; }
    else if (u < 12) { int v = u - 4;  qt2 = 4  + (v >> 1);  p = v & 1;  np = 2; }
    else if (u < 24) { int v = u - 12; qt2 = 8  + v / 3;     p = v % 3;  np = 3; }
    else             { int v = u - 24; qt2 = 12 + (v >> 2);  p = v & 3;  np = 4; }
    const int T = 2 * qt2 + 2;
    const int kt0 = p * 8;
    const int ktn = (p == np - 1) ? (T - kt0) : 8;

    const int t = threadIdx.x, w = t >> 6, lane = t & 63, quad = lane >> 4, l15 = lane & 15;
    const size_t base = (size_t)bh * (SEQ * HD);
    const int i0 = qt2 * 128 + w * 16;             // wave's 16 q-rows
    _Float16* Pw = Pl[w];
    const _Float16* Kg = kbuf + base;
    const _Float16* Vg = vbT + base;

    const int lr = lane >> 3, gg = lane & 7;
    const int gs = (gg ^ (lr & 7)) * 8;

    half8 aq[2];
    aq[0] = *(const half8*)(qb + base + (size_t)(i0 + l15) * HD + quad * 8);
    aq[1] = *(const half8*)(qb + base + (size_t)(i0 + l15) * HD + 32 + quad * 8);
    // fold 1/sqrt(HD) * log2(e) into Q: p = exp2(S)
    const _Float16 qs = (_Float16)(0.125f * 1.44269504f);
    #pragma unroll
    for (int k = 0; k < 8; ++k) { aq[0][k] *= qs; aq[1][k] *= qs; }

    const floatx4 z4 = {0.f, 0.f, 0.f, 0.f};
    floatx4 O[4];
    #pragma unroll
    for (int dt = 0; dt < 4; ++dt) O[dt] = z4;
    float l_one = 0.f;

    // prologue: stage first tile into buffer 0 (each wave: 1 K row-group + 1 V)
    {
        const int row = w * 8 + lr;
        gl_lds16(Kg + (size_t)(kt0 * 64 + row) * HD + gs,  &Kl[0][w * 512]);
        gl_lds16(Vg + (size_t)row * SEQ + kt0 * 64 + gs,   &Vl[0][w * 512]);
    }

    const int swz = l15 & 7;               // K/V read granule swizzle
    const int sswz = (l15 & 7) << 1;       // P granule swizzle (even -> b128-safe)
    const int srow = l15 * 64;             // P row base (this lane's q row)

    for (int it = 0; it < ktn; ++it) {
        const int kt = kt0 + it;
        const int buf = it & 1;
        const int j0 = kt * 64;
        __syncthreads();   // staging of `buf` drained; prev compute on buf^1 done

        if (it + 1 < ktn) {
            const _Float16* Kn = Kg + (size_t)(j0 + 64) * HD;
            const _Float16* Vn = Vg + (j0 + 64);
            const int row = w * 8 + lr;
            gl_lds16(Kn + (size_t)row * HD + gs,  &Kl[buf ^ 1][w * 512]);
            gl_lds16(Vn + (size_t)row * SEQ + gs, &Vl[buf ^ 1][w * 512]);
        }

        const bool active = (j0 <= i0 + 15);       // wave sees this tile
        if (!active) continue;                     // wave-uniform; barrier is above
        const bool diag = (j0 + 63 > i0);          // masking may be needed

        // S^T = K * Q^T : lane holds (k = nt*16 + quad*4 + r, q = l15)
        floatx4 S[4];
        #pragma unroll
        for (int nt = 0; nt < 4; ++nt) S[nt] = z4;
        __builtin_amdgcn_s_setprio(1);
        #pragma unroll
        for (int ks = 0; ks < 2; ++ks)
            #pragma unroll
            for (int nt = 0; nt < 4; ++nt) {
                half8 bk = *(const half8*)&Kl[buf][(nt * 16 + l15) * 64 +
                                                   (((ks * 4 + quad) ^ swz) << 3)];
                S[nt] = __builtin_amdgcn_mfma_f32_16x16x32_f16(bk, aq[ks], S[nt], 0, 0, 0);
            }
        __builtin_amdgcn_s_setprio(0);

        asm volatile("" ::: "memory");   // WAR: prior P-frag reads before new writes
        if (diag) {                      // masked path (zero where k > q)
            const int iq = i0 + l15;
            #pragma unroll
            for (int nt = 0; nt < 4; ++nt) {
                float pv[4];
                #pragma unroll
                for (int r = 0; r < 4; ++r) {
                    float pvv = exp2f(S[nt][r]);
                    if (j0 + nt * 16 + quad * 4 + r > iq) pvv = 0.f;
                    l_one += pvv;
                    pv[r] = pvv;
                }
                *(h4v*)&Pw[srow + (((nt * 4 + quad) ^ sswz) << 2)] =
                    pack4(pv[0], pv[1], pv[2], pv[3]);
            }
        } else {                         // interior tile: no masking ops
            #pragma unroll
            for (int nt = 0; nt < 4; ++nt) {
                float pv[4];
                #pragma unroll
                for (int r = 0; r < 4; ++r) {
                    float pvv = exp2f(S[nt][r]);
                    l_one += pvv;
                    pv[r] = pvv;
                }
                *(h4v*)&Pw[srow + (((nt * 4 + quad) ^ sswz) << 2)] =
                    pack4(pv[0], pv[1], pv[2], pv[3]);
            }
        }
        asm volatile("" ::: "memory");   // RAW: P writes before fragment reads

        __builtin_amdgcn_s_setprio(1);
        #pragma unroll
        for (int ks = 0; ks < 2; ++ks) {
            half8 ap = *(const half8*)&Pw[srow + (((((ks * 4 + quad) << 1)) ^ sswz) << 2)];
            #pragma unroll
            for (int dt = 0; dt < 4; ++dt) {
                half8 bv = *(const half8*)&Vl[buf][(dt * 16 + l15) * 64 +
                                                    (((ks * 4 + quad) ^ swz) << 3)];
                O[dt] = __builtin_amdgcn_mfma_f32_16x16x32_f16(ap, bv, O[dt], 0, 0, 0);
            }
        }
        __builtin_amdgcn_s_setprio(0);
    }

    // softmax denominator: lane holds partial for q = l15 over its k subset;
    // quads partition k -> reduce across quads only.
    float rs = l_one;
    rs += __shfl_xor(rs, 16);
    rs += __shfl_xor(rs, 32);

    if (np == 1) {
        const float inv = 1.0f / rs;     // inverse for q-row = l15
        const int bidx = bh / NH, h = bh - bidx * NH;
        #pragma unroll
        for (int r = 0; r < 4; ++r) {
            const float invr = __shfl(inv, quad * 4 + r);   // lane m holds row m
            const int i = i0 + quad * 4 + r;
            #pragma unroll
            for (int dt = 0; dt < 4; ++dt)
                sa[(size_t)(bidx * SEQ + i) * DIM + h * HD + dt * 16 + l15] =
                    (_Float16)(O[dt][r] * invr);
        }
    } else {
        // write partials: O (f16, 128x64) and l (fp32, 128), slot (bh, qt2, p)
        const size_t slot = ((size_t)(bh * 16 + qt2) * 4 + p);
        _Float16* Od = Opart + slot * 8192;
        float*    ld = lpart + slot * 128;
        if (lane < 16) ld[w * 16 + lane] = rs;
        #pragma unroll
        for (int r = 0; r < 4; ++r) {
            const int row = w * 16 + quad * 4 + r;
            #pragma unroll
            for (int dt = 0; dt < 4; ++dt)
                Od[row * 64 + dt * 16 + l15] = (_Float16)O[dt][r];
        }
    }
}

// ---------------------------------------------------------------------------
// Combine K-split partials: sa = (sum_p O_p) / (sum_p l_p) for qt2 >= 4.
// 128-row slots; 256 thr: row = t>>1, 32 d-cols per thread.
// ---------------------------------------------------------------------------
__global__ __launch_bounds__(256)
void attn_combine(const _Float16* __restrict__ Opart, const float* __restrict__ lpart,
                  _Float16* __restrict__ sa) {
    const int qt2 = 4 + blockIdx.x;
    const int bh = blockIdx.y;
    const int np = (2 * qt2 + 2 + 7) >> 3;
    const int t = threadIdx.x;
    const int row = t >> 1, d0 = (t & 1) * 32;
    const size_t slot0 = ((size_t)(bh * 16 + qt2) * 4);

    float lsum = 0.f;
    for (int p = 0; p < np; ++p) lsum += lpart[(slot0 + p) * 128 + row];

    float acc[32];
    #pragma unroll
    for (int k = 0; k < 32; ++k) acc[k] = 0.f;
    for (int p = 0; p < np; ++p) {
        const _Float16* src = Opart + (slot0 + p) * 8192 + row * 64 + d0;
        #pragma unroll
        for (int v = 0; v < 4; ++v) {
            half8 a = *(const half8*)(src + v * 8);
            #pragma unroll
            for (int k = 0; k < 8; ++k) acc[v * 8 + k] += (float)a[k];
        }
    }
    const float inv = 1.0f / lsum;
    const int bidx = bh / NH, h = bh - bidx * NH;
    _Float16* dst = sa + (size_t)(bidx * SEQ + qt2 * 128 + row) * DIM + h * HD + d0;
    #pragma unroll
    for (int v = 0; v < 4; ++v) {
        half8 o;
        #pragma unroll
        for (int k = 0; k < 8; ++k) o[k] = (_Float16)(acc[v * 8 + k] * inv);
        *(half8*)(dst + v * 8) = o;
    }
}

// ---------------------------------------------------------------------------
extern "C" void kernel_launch(void* const* d_in, const int* in_sizes, int n_in,
                              void* d_out, int out_size, void* d_ws, size_t ws_size,
                              hipStream_t stream) {
    (void)in_sizes; (void)n_in; (void)out_size; (void)ws_size;
    const float* x  = (const float*)d_in[0];
    const float* Wk = (const float*)d_in[1];
    const float* bk = (const float*)d_in[2];
    const float* Wp = (const float*)d_in[3];
    const float* bp = (const float*)d_in[4];
    float* out = (float*)d_out;

    _Float16* ws = (_Float16*)d_ws;
    const size_t per = (size_t)BB * NH * SEQ * HD;          // 3,145,728 halves
    const int nx = BB * SEQ * DIM;                          // 3,145,728
    const int nwk = NH * 3 * HD * DIM;                      // 1,769,472
    const int nwp = DIM * DIM;                              //   589,824
    _Float16* kb  = ws;
    _Float16* qb  = ws + per;
    _Float16* vbT = ws + 3 * per;                           // slot 2 unused
    _Float16* sa  = ws + 4 * per;
    _Float16* xh  = ws + 5 * per;
    _Float16* Wkh = xh + nx;
    _Float16* Wph = Wkh + nwk;
    _Float16* Opart = Wph + nwp;                            // 24*16*4*8192 f16
    float*    lpart = (float*)(Opart + (size_t)24 * 16 * 4 * 8192);

    const int nb0 = nx / 2048, nb1 = nwk / 2048, nb2 = nwp / 2048;
    cvt3<<<dim3(nb0 + nb1 + nb2), 256, 0, stream>>>(x, xh, nb0, Wk, Wkh, nb1, Wp, Wph);

    kqv_gemm2  <<<dim3(576), 512, 0, stream>>>(xh, Wkh, bk, kb, qb, vbT);
    attn_mfma  <<<dim3(960), 512, 0, stream>>>(qb, kb, vbT, sa, Opart, lpart);
    attn_combine<<<dim3(12, 24), 256, 0, stream>>>(Opart, lpart, sa);
    proj_gemm2 <<<dim3(192), 512, 0, stream>>>(sa, Wph, bp, out);
}